// Round 3
// baseline (36.987 us; speedup 1.0000x reference)
//
#include <hip/hip_runtime.h>
#include <hip/hip_cooperative_groups.h>
#include <math.h>

namespace cg = cooperative_groups;

// Problem constants (match reference file)
#define B_ROWS 8192
#define S_COLS 4096
// SIGMA = 1.0, K_FACTOR = 1.0, MARGIN = 0.0
//
// k = ceil(K_FACTOR / clamp(density, 0.1, inf)) with density in [0,1):
//   k in [2, 10] -> window half-width <= 10 -> fixed 21-wide window,
//   compile-time trip count, exp(-|o|) folded to constants.

__device__ __constant__ const float EXPW[11] = {
    1.0f,            0.36787944f,     0.13533528f,    0.049787068f,
    0.018315639f,    0.0067379470f,   0.0024787522f,  0.00091188197f,
    0.00033546262f,  0.00012340980f,  0.000045399930f
};

// Single cooperative kernel: 128 blocks x 64 threads = 8192 rows (1/thread).
// Phase 1: per-row loss, single-wave butterfly -> partial[block].
// grid.sync(), then block 0 reduces the 128 partials and writes the scalar.
__global__ __launch_bounds__(64) void awl_fused_kernel(
    const float* __restrict__ scores,
    const float* __restrict__ labels,
    const float* __restrict__ density,
    const int*   __restrict__ tstar,
    float* __restrict__ partial,
    float* __restrict__ out)
{
    const int tid = threadIdx.x;
    const int row = blockIdx.x * 64 + tid;           // always < 8192

    const float d  = fmaxf(density[row], 0.1f);
    const int   k  = (int)ceilf(1.0f / d);           // in [2,10]
    const int   ts = tstar[row];

    const float* __restrict__ srow = scores + (size_t)row * S_COLS;
    const float* __restrict__ lrow = labels + (size_t)row * S_COLS;

    // Issue all 42 loads up front (clamped addresses always in-bounds;
    // out-of-window contributions masked in the compute pass).
    float s_v[21], l_v[21];
    #pragma unroll
    for (int i = 0; i < 21; ++i) {
        const int t  = ts + (i - 10);
        const int tc = min(max(t, 0), S_COLS - 1);
        s_v[i] = srow[tc];
        l_v[i] = lrow[tc];
    }

    float wsum = 0.0f, rsum = 0.0f, dsum = 0.0f;
    int   rcnt = 0, dcnt = 0;

    #pragma unroll
    for (int i = 0; i < 21; ++i) {
        const int o    = i - 10;
        const int dist = (o < 0) ? -o : o;           // compile-time constant
        const float w  = EXPW[dist];                 // compile-time constant
        const int t    = ts + o;
        const bool in  = (dist <= k) & (t >= 0) & (t < S_COLS);
        if (in) {
            wsum += w;
            const float sw = s_v[i] * w;
            if (l_v[i] == 1.0f) { rsum += sw; rcnt++; }
            else                { dsum += sw; dcnt++; }
        }
    }

    float loss = 0.0f, validf = 0.0f;
    if (rcnt > 0 && dcnt > 0) {
        const float ref_avg = rsum / wsum / (float)rcnt;
        const float dev_avg = dsum / wsum / (float)dcnt;
        const float x = ref_avg - dev_avg;              // + MARGIN(=0)
        // -log_sigmoid(x) = softplus(-x), numerically stable
        loss   = fmaxf(-x, 0.0f) + log1pf(expf(-fabsf(x)));
        validf = 1.0f;
    }

    // single-wave butterfly reduction (deterministic)
    #pragma unroll
    for (int off = 32; off > 0; off >>= 1) {
        loss   += __shfl_down(loss,   off, 64);
        validf += __shfl_down(validf, off, 64);
    }
    if (tid == 0) {
        partial[blockIdx.x]       = loss;
        partial[128 + blockIdx.x] = validf;
    }

    cg::this_grid().sync();

    if (blockIdx.x == 0) {
        float l = partial[tid]       + partial[tid + 64];
        float c = partial[128 + tid] + partial[128 + tid + 64];
        #pragma unroll
        for (int off = 32; off > 0; off >>= 1) {
            l += __shfl_down(l, off, 64);
            c += __shfl_down(c, off, 64);
        }
        if (tid == 0) {
            out[0] = (c > 0.0f) ? (l / fmaxf(c, 1.0f)) : 0.0f;
        }
    }
}

extern "C" void kernel_launch(void* const* d_in, const int* in_sizes, int n_in,
                              void* d_out, int out_size, void* d_ws, size_t ws_size,
                              hipStream_t stream)
{
    const float* scores  = (const float*)d_in[0];  // [B,S] f32
    const float* labels  = (const float*)d_in[1];  // [B,S] f32 (0/1)
    const float* density = (const float*)d_in[2];  // [B]   f32
    const int*   tstar   = (const int*)  d_in[3];  // [B]   i32
    float*       out     = (float*)d_out;          // scalar f32
    float*       partial = (float*)d_ws;           // 256 floats used

    void* args[] = { (void*)&scores, (void*)&labels, (void*)&density,
                     (void*)&tstar,  (void*)&partial, (void*)&out };
    hipLaunchCooperativeKernel((void*)awl_fused_kernel,
                               dim3(B_ROWS / 64), dim3(64),
                               args, 0, stream);
}

// Round 4
// 19.298 us; speedup vs baseline: 1.9166x; 1.9166x over previous
//
#include <hip/hip_runtime.h>
#include <math.h>

// Problem constants (match reference file)
#define B_ROWS 8192
#define S_COLS 4096
// SIGMA = 1.0, K_FACTOR = 1.0, MARGIN = 0.0
//
// k = ceil(K_FACTOR / clamp(density, 0.1, inf)) with density in [0,1):
//   k in [2, 10] -> window half-width <= 10 -> fixed 21-wide window,
//   compile-time trip count, exp(-|o|) folded to constants.

__device__ __constant__ const float EXPW[11] = {
    1.0f,            0.36787944f,     0.13533528f,    0.049787068f,
    0.018315639f,    0.0067379470f,   0.0024787522f,  0.00091188197f,
    0.00033546262f,  0.00012340980f,  0.000045399930f
};

// Single regular kernel: 128 blocks x 64 threads = 8192 rows (1 row/thread).
// Each block wave-reduces its 64 row losses, publishes (loss, valid) partials
// with agent-scope stores, then bumps a device-scope counter. The block that
// sees old==127 (all partials published) reduces the fixed 128 slots in a
// fixed tree order -> deterministic scalar, regardless of which block is last.
// The counter is zeroed by a 4-byte memset node each call.
__global__ __launch_bounds__(64) void awl_fused_kernel(
    const float* __restrict__ scores,
    const float* __restrict__ labels,
    const float* __restrict__ density,
    const int*   __restrict__ tstar,
    float* __restrict__ partial,
    unsigned int* __restrict__ counter,
    float* __restrict__ out)
{
    const int tid = threadIdx.x;
    const int row = blockIdx.x * 64 + tid;           // always < 8192

    const float d  = fmaxf(density[row], 0.1f);
    const int   k  = (int)ceilf(1.0f / d);           // in [2,10]
    const int   ts = tstar[row];

    const float* __restrict__ srow = scores + (size_t)row * S_COLS;
    const float* __restrict__ lrow = labels + (size_t)row * S_COLS;

    // Issue all 42 loads up front (clamped addresses always in-bounds;
    // out-of-window contributions masked in the compute pass).
    float s_v[21], l_v[21];
    #pragma unroll
    for (int i = 0; i < 21; ++i) {
        const int t  = ts + (i - 10);
        const int tc = min(max(t, 0), S_COLS - 1);
        s_v[i] = srow[tc];
        l_v[i] = lrow[tc];
    }

    float wsum = 0.0f, rsum = 0.0f, dsum = 0.0f;
    int   rcnt = 0, dcnt = 0;

    #pragma unroll
    for (int i = 0; i < 21; ++i) {
        const int o    = i - 10;
        const int dist = (o < 0) ? -o : o;           // compile-time constant
        const float w  = EXPW[dist];                 // compile-time constant
        const int t    = ts + o;
        const bool in  = (dist <= k) & (t >= 0) & (t < S_COLS);
        if (in) {
            wsum += w;
            const float sw = s_v[i] * w;
            if (l_v[i] == 1.0f) { rsum += sw; rcnt++; }
            else                { dsum += sw; dcnt++; }
        }
    }

    float loss = 0.0f, validf = 0.0f;
    if (rcnt > 0 && dcnt > 0) {
        const float ref_avg = rsum / wsum / (float)rcnt;
        const float dev_avg = dsum / wsum / (float)dcnt;
        const float x = ref_avg - dev_avg;              // + MARGIN(=0)
        // -log_sigmoid(x) = softplus(-x), numerically stable
        loss   = fmaxf(-x, 0.0f) + log1pf(expf(-fabsf(x)));
        validf = 1.0f;
    }

    // single-wave butterfly reduction (deterministic)
    #pragma unroll
    for (int off = 32; off > 0; off >>= 1) {
        loss   += __shfl_down(loss,   off, 64);
        validf += __shfl_down(validf, off, 64);
    }

    // Publish this block's partial at device scope.
    if (tid == 0) {
        __hip_atomic_store(&partial[blockIdx.x],       loss,
                           __ATOMIC_RELAXED, __HIP_MEMORY_SCOPE_AGENT);
        __hip_atomic_store(&partial[128 + blockIdx.x], validf,
                           __ATOMIC_RELAXED, __HIP_MEMORY_SCOPE_AGENT);
    }
    __threadfence();   // release partials before the counter bump

    unsigned int old = 0;
    if (tid == 0) {
        old = __hip_atomic_fetch_add(counter, 1u,
                                     __ATOMIC_ACQ_REL, __HIP_MEMORY_SCOPE_AGENT);
    }
    old = __shfl(old, 0, 64);

    if (old == 127u) {
        // Last block: every partial is published (acq_rel pairing).
        float l = __hip_atomic_load(&partial[tid],
                                    __ATOMIC_RELAXED, __HIP_MEMORY_SCOPE_AGENT)
                + __hip_atomic_load(&partial[tid + 64],
                                    __ATOMIC_RELAXED, __HIP_MEMORY_SCOPE_AGENT);
        float c = __hip_atomic_load(&partial[128 + tid],
                                    __ATOMIC_RELAXED, __HIP_MEMORY_SCOPE_AGENT)
                + __hip_atomic_load(&partial[128 + tid + 64],
                                    __ATOMIC_RELAXED, __HIP_MEMORY_SCOPE_AGENT);
        #pragma unroll
        for (int off = 32; off > 0; off >>= 1) {
            l += __shfl_down(l, off, 64);
            c += __shfl_down(c, off, 64);
        }
        if (tid == 0) {
            out[0] = (c > 0.0f) ? (l / fmaxf(c, 1.0f)) : 0.0f;
        }
    }
}

extern "C" void kernel_launch(void* const* d_in, const int* in_sizes, int n_in,
                              void* d_out, int out_size, void* d_ws, size_t ws_size,
                              hipStream_t stream)
{
    const float* scores  = (const float*)d_in[0];  // [B,S] f32
    const float* labels  = (const float*)d_in[1];  // [B,S] f32 (0/1)
    const float* density = (const float*)d_in[2];  // [B]   f32
    const int*   tstar   = (const int*)  d_in[3];  // [B]   i32
    float*       out     = (float*)d_out;          // scalar f32
    float*       partial = (float*)d_ws;           // 256 floats
    unsigned int* counter = (unsigned int*)((char*)d_ws + 1024);

    hipMemsetAsync(counter, 0, sizeof(unsigned int), stream);
    awl_fused_kernel<<<B_ROWS / 64, 64, 0, stream>>>(
        scores, labels, density, tstar, partial, counter, out);
}

// Round 5
// 11.308 us; speedup vs baseline: 3.2709x; 1.7066x over previous
//
#include <hip/hip_runtime.h>
#include <math.h>

// Problem constants (match reference file)
#define B_ROWS 8192
#define S_COLS 4096
// SIGMA = 1.0, K_FACTOR = 1.0, MARGIN = 0.0
//
// k = ceil(K_FACTOR / clamp(density, 0.1, inf)) with density in [0,1):
//   k in [2, 10] -> window half-width <= 10.
//
// Gather strategy: the 21-wide window [ts-10, ts+10] always lies inside the
// 24-element aligned range starting at base = clamp((ts-10) & ~3, 0, S-24):
//   base <= ts-10  (masking only lowers, clamp cases proven at edges), and
//   base >= ts-13  => base+23 >= ts+10.  base is a multiple of 4 -> float4
//   loads are 16B-aligned.  6 float4 loads per array = 12 VMEM instrs
//   (vs 42 scalar), one latency batch, no per-element address clamping.

// Kernel 1: one thread per row. 128 blocks x 64 threads = 8192 rows.
__global__ __launch_bounds__(64) void awl_rows_kernel(
    const float* __restrict__ scores,
    const float* __restrict__ labels,
    const float* __restrict__ density,
    const int*   __restrict__ tstar,
    float* __restrict__ partial)
{
    const int tid = threadIdx.x;
    const int row = blockIdx.x * 64 + tid;           // always < 8192

    const float d  = fmaxf(density[row], 0.1f);
    const int   k  = (int)ceilf(1.0f / d);           // in [2,10]
    const int   ts = tstar[row];

    const int base = min(max((ts - 10) & ~3, 0), S_COLS - 24);

    const float4* __restrict__ srow =
        (const float4*)(scores + (size_t)row * S_COLS + base);
    const float4* __restrict__ lrow =
        (const float4*)(labels + (size_t)row * S_COLS + base);

    // Issue all 12 vector loads up front -> one HBM latency batch.
    float4 s_v[6], l_v[6];
    #pragma unroll
    for (int j = 0; j < 6; ++j) {
        s_v[j] = srow[j];
        l_v[j] = lrow[j];
    }

    float wsum = 0.0f, rsum = 0.0f, dsum = 0.0f;
    int   rcnt = 0, dcnt = 0;

    #pragma unroll
    for (int i = 0; i < 24; ++i) {
        const float s   = ((const float*)&s_v[i / 4])[i % 4];  // compile-time idx
        const float lab = ((const float*)&l_v[i / 4])[i % 4];
        const int   t    = base + i;
        const int   dist = (t >= ts) ? (t - ts) : (ts - t);
        if (dist <= k) {                       // t is always in [0, S) here
            const float w = __expf(-(float)dist);
            wsum += w;
            const float sw = s * w;
            if (lab == 1.0f) { rsum += sw; rcnt++; }
            else             { dsum += sw; dcnt++; }
        }
    }

    float loss = 0.0f, validf = 0.0f;
    if (rcnt > 0 && dcnt > 0) {
        const float ref_avg = rsum / wsum / (float)rcnt;
        const float dev_avg = dsum / wsum / (float)dcnt;
        const float x = ref_avg - dev_avg;              // + MARGIN(=0)
        // -log_sigmoid(x) = softplus(-x), numerically stable
        loss   = fmaxf(-x, 0.0f) + log1pf(expf(-fabsf(x)));
        validf = 1.0f;
    }

    // single-wave butterfly reduction (deterministic)
    #pragma unroll
    for (int off = 32; off > 0; off >>= 1) {
        loss   += __shfl_down(loss,   off, 64);
        validf += __shfl_down(validf, off, 64);
    }
    if (tid == 0) {
        partial[blockIdx.x]       = loss;
        partial[128 + blockIdx.x] = validf;
    }
}

// Kernel 2: single 64-thread wave reduces the 128 partials deterministically.
__global__ __launch_bounds__(64) void awl_final_kernel(
    const float* __restrict__ partial,
    float* __restrict__ out)
{
    const int tid = threadIdx.x;
    float l = partial[tid]       + partial[tid + 64];
    float c = partial[128 + tid] + partial[128 + tid + 64];
    #pragma unroll
    for (int off = 32; off > 0; off >>= 1) {
        l += __shfl_down(l, off, 64);
        c += __shfl_down(c, off, 64);
    }
    if (tid == 0) {
        out[0] = (c > 0.0f) ? (l / fmaxf(c, 1.0f)) : 0.0f;
    }
}

extern "C" void kernel_launch(void* const* d_in, const int* in_sizes, int n_in,
                              void* d_out, int out_size, void* d_ws, size_t ws_size,
                              hipStream_t stream)
{
    const float* scores  = (const float*)d_in[0];  // [B,S] f32
    const float* labels  = (const float*)d_in[1];  // [B,S] f32 (0/1)
    const float* density = (const float*)d_in[2];  // [B]   f32
    const int*   tstar   = (const int*)  d_in[3];  // [B]   i32
    float*       out     = (float*)d_out;          // scalar f32
    float*       partial = (float*)d_ws;           // 256 floats used

    awl_rows_kernel<<<B_ROWS / 64, 64, 0, stream>>>(scores, labels, density, tstar, partial);
    awl_final_kernel<<<1, 64, 0, stream>>>(partial, out);
}

// Round 6
// 10.914 us; speedup vs baseline: 3.3888x; 1.0360x over previous
//
#include <hip/hip_runtime.h>
#include <math.h>

// Problem constants (match reference file)
#define B_ROWS 8192
#define S_COLS 4096
// SIGMA = 1.0, K_FACTOR = 1.0, MARGIN = 0.0
//
// k = ceil(K_FACTOR / clamp(density, 0.1, inf)) with density in [0,1):
//   k in [2, 10] -> window half-width <= 10 -> fixed 21-wide window,
//   compile-time trip count, exp(-|o|) folded to constants.
//
// Structure ledger (measured):
//   2 plain kernels (this file)          10.9 us   <- best
//   2 plain kernels, float4 gather       11.3 us   (neutral; VMEM not limiter)
//   1 cooperative kernel + grid.sync     37.0 us   (coop node ~ +26 us)
//   memsetAsync + last-block-done        19.3 us   (handshake > kernel node)
// Both kernels are launch-overhead bound (~8-9 us of the total); utilization
// counters ~0 by design.

// exp(-|o|) as f32 constants (SIGMA = 1): index by |o| (compile-time only).
__device__ __constant__ const float EXPW[11] = {
    1.0f,            0.36787944f,     0.13533528f,    0.049787068f,
    0.018315639f,    0.0067379470f,   0.0024787522f,  0.00091188197f,
    0.00033546262f,  0.00012340980f,  0.000045399930f
};

// Kernel 1: one thread per row. 128 blocks x 64 threads = 8192 rows.
// Fixed 21-wide window, fully unrolled: all 42 gathered loads go into the
// vmcnt queue together -> one HBM latency batch.
__global__ __launch_bounds__(64) void awl_rows_kernel(
    const float* __restrict__ scores,
    const float* __restrict__ labels,
    const float* __restrict__ density,
    const int*   __restrict__ tstar,
    float* __restrict__ partial)
{
    const int row = blockIdx.x * 64 + threadIdx.x;   // always < 8192

    const float d  = fmaxf(density[row], 0.1f);
    const int   k  = (int)ceilf(1.0f / d);           // in [2,10]
    const int   ts = tstar[row];

    const float* __restrict__ srow = scores + (size_t)row * S_COLS;
    const float* __restrict__ lrow = labels + (size_t)row * S_COLS;

    // Issue all loads up front (clamped addresses are always in-bounds;
    // out-of-window lanes are masked in the compute pass).
    float s_v[21], l_v[21];
    #pragma unroll
    for (int i = 0; i < 21; ++i) {
        const int t  = ts + (i - 10);
        const int tc = min(max(t, 0), S_COLS - 1);
        s_v[i] = srow[tc];
        l_v[i] = lrow[tc];
    }

    float wsum = 0.0f, rsum = 0.0f, dsum = 0.0f;
    int   rcnt = 0, dcnt = 0;

    #pragma unroll
    for (int i = 0; i < 21; ++i) {
        const int o    = i - 10;
        const int dist = (o < 0) ? -o : o;           // compile-time constant
        const float w  = EXPW[dist];                 // compile-time constant
        const int t    = ts + o;
        const bool in  = (dist <= k) & (t >= 0) & (t < S_COLS);
        if (in) {
            wsum += w;
            const float sw = s_v[i] * w;
            if (l_v[i] == 1.0f) { rsum += sw; rcnt++; }
            else                { dsum += sw; dcnt++; }
        }
    }

    float loss = 0.0f, validf = 0.0f;
    if (rcnt > 0 && dcnt > 0) {
        const float ref_avg = rsum / wsum / (float)rcnt;
        const float dev_avg = dsum / wsum / (float)dcnt;
        const float x = ref_avg - dev_avg;              // + MARGIN(=0)
        // -log_sigmoid(x) = softplus(-x), numerically stable
        loss   = fmaxf(-x, 0.0f) + log1pf(expf(-fabsf(x)));
        validf = 1.0f;
    }

    // single-wave butterfly reduction (deterministic)
    #pragma unroll
    for (int off = 32; off > 0; off >>= 1) {
        loss   += __shfl_down(loss,   off, 64);
        validf += __shfl_down(validf, off, 64);
    }
    if (threadIdx.x == 0) {
        partial[blockIdx.x]       = loss;
        partial[128 + blockIdx.x] = validf;
    }
}

// Kernel 2: single 64-thread wave reduces the 128 partials deterministically.
__global__ __launch_bounds__(64) void awl_final_kernel(
    const float* __restrict__ partial,
    float* __restrict__ out)
{
    const int tid = threadIdx.x;
    float l = partial[tid]       + partial[tid + 64];
    float c = partial[128 + tid] + partial[128 + tid + 64];
    #pragma unroll
    for (int off = 32; off > 0; off >>= 1) {
        l += __shfl_down(l, off, 64);
        c += __shfl_down(c, off, 64);
    }
    if (tid == 0) {
        out[0] = (c > 0.0f) ? (l / fmaxf(c, 1.0f)) : 0.0f;
    }
}

extern "C" void kernel_launch(void* const* d_in, const int* in_sizes, int n_in,
                              void* d_out, int out_size, void* d_ws, size_t ws_size,
                              hipStream_t stream)
{
    const float* scores  = (const float*)d_in[0];  // [B,S] f32
    const float* labels  = (const float*)d_in[1];  // [B,S] f32 (0/1)
    const float* density = (const float*)d_in[2];  // [B]   f32
    const int*   tstar   = (const int*)  d_in[3];  // [B]   i32
    float*       out     = (float*)d_out;          // scalar f32
    float*       partial = (float*)d_ws;           // 256 floats used

    awl_rows_kernel<<<B_ROWS / 64, 64, 0, stream>>>(scores, labels, density, tstar, partial);
    awl_final_kernel<<<1, 64, 0, stream>>>(partial, out);
}